// Round 5
// baseline (1371.339 us; speedup 1.0000x reference)
//
#include <hip/hip_runtime.h>
#include <hip/hip_bf16.h>
#include <math.h>

#define L_SEQ 8192
#define NFFT  16384
#define NPAD  16896   // NFFT + NFFT/32 padding (complex elements)
#define F_DIM 768
#define D_DIM 768
#define C_IN  2304   // INNER = F*(ORDER+1)
#define NORD  2
#define PI2   6.2831853071795864769f

typedef unsigned short u16;
typedef unsigned int u32;
typedef __attribute__((ext_vector_type(8))) short bf16x8;
typedef __attribute__((ext_vector_type(4))) float f32x4;
struct __align__(8) U16x4 { u16 x, y, z, w; };

__device__ __forceinline__ float bf2f(u16 v) {
  unsigned u = ((unsigned)v) << 16; float f; __builtin_memcpy(&f, &u, 4); return f;
}
__device__ __forceinline__ u16 f2bf(float f) {
  __hip_bfloat16 h = __float2bfloat16(f); u16 r; __builtin_memcpy(&r, &h, 2); return r;
}
__device__ __forceinline__ float u2f(u32 u) { float f; __builtin_memcpy(&f, &u, 4); return f; }

// LDS pad (complex units): +1 complex every 32 -> all FFT strides <=2-way
__device__ __forceinline__ int PAD(int i) { return i + (i >> 5); }

__device__ __forceinline__ void rot3(float ang, float& c1, float& s1,
                                     float& c2, float& s2, float& c3, float& s3)
{
  __sincosf(ang, &s1, &c1);
  c2 = c1 * c1 - s1 * s1; s2 = 2.0f * c1 * s1;
  c3 = c1 * c2 - s1 * s2; s3 = c1 * s2 + s1 * c2;
}

// ===========================================================================
// Radix-4 FFT over padded float2 LDS, N = 16384 = 4^7, fused stage pairs.
// fwd partial: DIF stages (12,10)(8,6)(4,2) -- caller fuses final stage 0.
// inv: caller fuses stage 0; inv_mid does (2,4)(6,8); caller fuses (10,12).
// Algebra transcribed 1:1 from the round-2/3/4 verified routines.
// ===========================================================================
template<int NT>
__device__ __forceinline__ void fft4_fwd_partial(float2* c, int tid)
{
  #pragma unroll
  for (int lq = 12; lq >= 4; lq -= 4) {      // fused pair: stage lq then lq-2
    const int q  = 1 << lq;
    const int q4 = q >> 2;
    const float stw1 = -PI2 / (float)(q << 2);
    const float stw2 = -PI2 / (float)q;
    for (int g = tid; g < NFFT / 16; g += NT) {
      const int j    = g & (q4 - 1);
      const int base = ((g >> (lq - 2)) << (lq + 2)) + j;
      float2 x[4][4];                        // [k][m]: pos = base + m*q4 + k*q
      #pragma unroll
      for (int k = 0; k < 4; ++k)
        #pragma unroll
        for (int m = 0; m < 4; ++m)
          x[k][m] = c[PAD(base + m * q4 + k * q)];
      #pragma unroll
      for (int m = 0; m < 4; ++m) {          // layer 1: stage lq, j1 = j+m*q4
        float t0r = x[0][m].x + x[2][m].x, t0i = x[0][m].y + x[2][m].y;
        float t1r = x[0][m].x - x[2][m].x, t1i = x[0][m].y - x[2][m].y;
        float t2r = x[1][m].x + x[3][m].x, t2i = x[1][m].y + x[3][m].y;
        float t3r = x[1][m].x - x[3][m].x, t3i = x[1][m].y - x[3][m].y;
        float y0r = t0r + t2r, y0i = t0i + t2i;
        float y1r = t1r + t3i, y1i = t1i - t3r;
        float y2r = t0r - t2r, y2i = t0i - t2i;
        float y3r = t1r - t3i, y3i = t1i + t3r;
        float c1, s1, c2, s2, c3, s3;
        rot3(stw1 * (float)(j + m * q4), c1, s1, c2, s2, c3, s3);
        x[0][m] = make_float2(y0r, y0i);
        x[1][m] = make_float2(y1r * c1 - y1i * s1, y1r * s1 + y1i * c1);
        x[2][m] = make_float2(y2r * c2 - y2i * s2, y2r * s2 + y2i * c2);
        x[3][m] = make_float2(y3r * c3 - y3i * s3, y3r * s3 + y3i * c3);
      }
      float c1, s1, c2, s2, c3, s3;          // layer 2: stage lq-2, j2 = j
      rot3(stw2 * (float)j, c1, s1, c2, s2, c3, s3);
      #pragma unroll
      for (int k = 0; k < 4; ++k) {
        float t0r = x[k][0].x + x[k][2].x, t0i = x[k][0].y + x[k][2].y;
        float t1r = x[k][0].x - x[k][2].x, t1i = x[k][0].y - x[k][2].y;
        float t2r = x[k][1].x + x[k][3].x, t2i = x[k][1].y + x[k][3].y;
        float t3r = x[k][1].x - x[k][3].x, t3i = x[k][1].y - x[k][3].y;
        float y0r = t0r + t2r, y0i = t0i + t2i;
        float y1r = t1r + t3i, y1i = t1i - t3r;
        float y2r = t0r - t2r, y2i = t0i - t2i;
        float y3r = t1r - t3i, y3i = t1i + t3r;
        const int i0 = base + k * q;
        c[PAD(i0         )] = make_float2(y0r, y0i);
        c[PAD(i0 +     q4)] = make_float2(y1r*c1 - y1i*s1, y1r*s1 + y1i*c1);
        c[PAD(i0 + 2 * q4)] = make_float2(y2r*c2 - y2i*s2, y2r*s2 + y2i*c2);
        c[PAD(i0 + 3 * q4)] = make_float2(y3r*c3 - y3i*s3, y3r*s3 + y3i*c3);
      }
    }
    __syncthreads();
  }
}

template<int NT>
__device__ __forceinline__ void fft4_inv_mid(float2* c, int tid)
{
  #pragma unroll
  for (int lq = 2; lq <= 6; lq += 4) {       // fused pair: stage lq then lq+2
    const int q = 1 << lq;
    const int Q = q << 2;
    const float stw1 = PI2 / (float)(q << 2);
    const float stw2 = PI2 / (float)(Q << 2);
    for (int g = tid; g < NFFT / 16; g += NT) {
      const int j    = g & (q - 1);
      const int base = ((g >> lq) << (lq + 4)) + j;
      float2 x[4][4];                        // [k][m]: pos = base + m*q + k*Q
      #pragma unroll
      for (int k = 0; k < 4; ++k)
        #pragma unroll
        for (int m = 0; m < 4; ++m)
          x[k][m] = c[PAD(base + m * q + k * Q)];
      {                                       // layer 1: stage lq, twiddle j
        float c1, s1, c2, s2, c3, s3;
        rot3(stw1 * (float)j, c1, s1, c2, s2, c3, s3);
        #pragma unroll
        for (int k = 0; k < 4; ++k) {
          float u0r = x[k][0].x, u0i = x[k][0].y;
          float u1r = x[k][1].x*c1 - x[k][1].y*s1, u1i = x[k][1].x*s1 + x[k][1].y*c1;
          float u2r = x[k][2].x*c2 - x[k][2].y*s2, u2i = x[k][2].x*s2 + x[k][2].y*c2;
          float u3r = x[k][3].x*c3 - x[k][3].y*s3, u3i = x[k][3].x*s3 + x[k][3].y*c3;
          float e0r = u0r + u2r, e0i = u0i + u2i;
          float e1r = u0r - u2r, e1i = u0i - u2i;
          float f0r = u1r + u3r, f0i = u1i + u3i;
          float f1r = u1r - u3r, f1i = u1i - u3i;
          x[k][0] = make_float2(e0r + f0r, e0i + f0i);
          x[k][1] = make_float2(e1r - f1i, e1i + f1r);
          x[k][2] = make_float2(e0r - f0r, e0i - f0i);
          x[k][3] = make_float2(e1r + f1i, e1i - f1r);
        }
      }
      #pragma unroll
      for (int m = 0; m < 4; ++m) {           // layer 2: stage lq+2, j2 = j+m*q
        float c1, s1, c2, s2, c3, s3;
        rot3(stw2 * (float)(j + m * q), c1, s1, c2, s2, c3, s3);
        float u0r = x[0][m].x, u0i = x[0][m].y;
        float u1r = x[1][m].x*c1 - x[1][m].y*s1, u1i = x[1][m].x*s1 + x[1][m].y*c1;
        float u2r = x[2][m].x*c2 - x[2][m].y*s2, u2i = x[2][m].x*s2 + x[2][m].y*c2;
        float u3r = x[3][m].x*c3 - x[3][m].y*s3, u3i = x[3][m].x*s3 + x[3][m].y*c3;
        float e0r = u0r + u2r, e0i = u0i + u2i;
        float e1r = u0r - u2r, e1i = u0i - u2i;
        float f0r = u1r + u3r, f0i = u1i + u3i;
        float f1r = u1r - u3r, f1i = u1i - u3i;
        const int i0 = base + m * q;
        c[PAD(i0        )] = make_float2(e0r + f0r, e0i + f0i);
        c[PAD(i0 +     Q)] = make_float2(e1r - f1i, e1i + f1r);
        c[PAD(i0 + 2 * Q)] = make_float2(e0r - f0r, e0i - f0i);
        c[PAD(i0 + 3 * Q)] = make_float2(e1r + f1i, e1i - f1r);
      }
    }
    __syncthreads();
  }
}

// depthwise conv3 on a bf16 row, SAME padding (XLA cross-correlation)
__device__ __forceinline__ float conv3b(const u16* __restrict__ row, int t,
                                        float w0, float w1, float w2, float sb)
{
  float l = (t > 0)         ? bf2f(row[t - 1]) : 0.0f;
  float c = bf2f(row[t]);
  float r = (t < L_SEQ - 1) ? bf2f(row[t + 1]) : 0.0f;
  return w0 * l + w1 * c + w2 * r + sb;
}

// ===========================================================================
// Prep kernels (unchanged)
// ===========================================================================
__global__ __launch_bounds__(256)
void cast_bf16_kernel(const float* __restrict__ in, u16* __restrict__ out, int n4)
{
  int i = blockIdx.x * 256 + threadIdx.x;
  if (i < n4) {
    float4 v = ((const float4*)in)[i];
    U16x4 w; w.x = f2bf(v.x); w.y = f2bf(v.y); w.z = f2bf(v.z); w.w = f2bf(v.w);
    ((U16x4*)out)[i] = w;
  }
}

__global__ __launch_bounds__(256)
void transpose_cast_kernel(const float* __restrict__ in, u16* __restrict__ out,
                           int K, int N)   // in [K][N] fp32 -> out [N][K] bf16
{
  __shared__ u16 tile[32][33];
  const int n0 = blockIdx.x * 32, k0 = blockIdx.y * 32;
  const int tx = threadIdx.x & 31, ty = threadIdx.x >> 5;
  #pragma unroll
  for (int i = 0; i < 32; i += 8)
    tile[ty + i][tx] = f2bf(in[(size_t)(k0 + ty + i) * N + n0 + tx]);
  __syncthreads();
  #pragma unroll
  for (int i = 0; i < 32; i += 8)
    out[(size_t)(n0 + ty + i) * K + k0 + tx] = tile[tx][ty + i];
}

__global__ __launch_bounds__(256)
void transpose_v_kernel(const u16* __restrict__ vb, u16* __restrict__ out)
{
  __shared__ u16 t2[64][65];
  const int m0 = blockIdx.x * 64, f0 = blockIdx.y * 64;
  const int tx = threadIdx.x & 63, ty = threadIdx.x >> 6;
  #pragma unroll
  for (int i = 0; i < 64; i += 4)
    t2[ty + i][tx] = vb[(size_t)(f0 + ty + i) * (2 * NFFT) + m0 + tx];
  __syncthreads();
  #pragma unroll
  for (int i = 0; i < 64; i += 4)
    out[(size_t)(m0 + ty + i) * F_DIM + f0 + tx] = t2[tx][ty + i];
}

// ===========================================================================
// MFMA GEMM (unchanged, verified rounds 3-4)
// ===========================================================================
template<int N_DIM, int K_DIM, int WMODE>
__global__ __launch_bounds__(256)
void mfma_gemm_kernel(const u16* __restrict__ A, const u16* __restrict__ B,
                      const float* __restrict__ bias, void* __restrict__ Cv)
{
  constexpr int BK = 64;
  __shared__ u16 As[128 * BK];
  __shared__ u16 Bs[128 * BK];
  const int tid  = threadIdx.x;
  const int lane = tid & 63;
  const int wid  = tid >> 6;
  const int m0 = blockIdx.x * 128;
  const int n0 = blockIdx.y * 128;

  const u16* aPtr[4]; const u16* bPtr[4];
  #pragma unroll
  for (int i = 0; i < 4; ++i) {
    const int g = tid + (i << 8);
    aPtr[i] = A + (size_t)(m0 + (g >> 3)) * K_DIM + ((g & 7) << 3);
    bPtr[i] = B + (size_t)(n0 + (g >> 3)) * K_DIM + ((g & 7) << 3);
  }

  const int wm = (wid & 1) << 6;
  const int wn = (wid >> 1) << 6;
  int aoff[4], boff[4];
  #pragma unroll
  for (int f = 0; f < 4; ++f) {
    aoff[f] = (wm + f * 16 + (lane & 15)) * BK + ((lane >> 4) << 3);
    boff[f] = (wn + f * 16 + (lane & 15)) * BK + ((lane >> 4) << 3);
  }

  f32x4 acc[4][4];
  #pragma unroll
  for (int i = 0; i < 4; ++i)
    #pragma unroll
    for (int j = 0; j < 4; ++j)
      acc[i][j] = (f32x4){0.f, 0.f, 0.f, 0.f};

  for (int k0 = 0; k0 < K_DIM; k0 += BK) {
    #pragma unroll
    for (int i = 0; i < 4; ++i) {
      __builtin_amdgcn_global_load_lds(
          (const __attribute__((address_space(1))) void*)aPtr[i],
          (__attribute__((address_space(3))) void*)&As[(((wid << 6) + (i << 8)) << 3)],
          16, 0, 0);
      aPtr[i] += BK;
    }
    #pragma unroll
    for (int i = 0; i < 4; ++i) {
      __builtin_amdgcn_global_load_lds(
          (const __attribute__((address_space(1))) void*)bPtr[i],
          (__attribute__((address_space(3))) void*)&Bs[(((wid << 6) + (i << 8)) << 3)],
          16, 0, 0);
      bPtr[i] += BK;
    }
    __syncthreads();
    #pragma unroll
    for (int kk = 0; kk < 2; ++kk) {
      bf16x8 af[4], bg[4];
      #pragma unroll
      for (int f = 0; f < 4; ++f) af[f] = *(const bf16x8*)&As[aoff[f] + kk * 32];
      #pragma unroll
      for (int f = 0; f < 4; ++f) bg[f] = *(const bf16x8*)&Bs[boff[f] + kk * 32];
      #pragma unroll
      for (int fm = 0; fm < 4; ++fm)
        #pragma unroll
        for (int fn = 0; fn < 4; ++fn)
          acc[fm][fn] = __builtin_amdgcn_mfma_f32_16x16x32_bf16(
              af[fm], bg[fn], acc[fm][fn], 0, 0, 0);
    }
    __syncthreads();
  }

  if (WMODE == 0) {
    u16* C = (u16*)Cv;
    const int b = m0 >> 13;
    const int tbase = (m0 & (L_SEQ - 1)) + wm + ((lane >> 4) << 2);
    #pragma unroll
    for (int fn = 0; fn < 4; ++fn) {
      const int n = n0 + wn + fn * 16 + (lane & 15);
      const float bv = bias[n];
      u16* row = C + ((size_t)b * N_DIM + n) * L_SEQ;
      #pragma unroll
      for (int fm = 0; fm < 4; ++fm) {
        f32x4 v = acc[fm][fn];
        U16x4 w;
        w.x = f2bf(v[0] + bv); w.y = f2bf(v[1] + bv);
        w.z = f2bf(v[2] + bv); w.w = f2bf(v[3] + bv);
        *(U16x4*)&row[tbase + fm * 16] = w;
      }
    }
  } else {
    float* C = (float*)Cv;
    #pragma unroll
    for (int fn = 0; fn < 4; ++fn) {
      const int n = n0 + wn + fn * 16 + (lane & 15);
      const float bv = bias[n];
      #pragma unroll
      for (int fm = 0; fm < 4; ++fm) {
        const int mb = m0 + wm + fm * 16 + ((lane >> 4) << 2);
        f32x4 v = acc[fm][fn];
        #pragma unroll
        for (int r = 0; r < 4; ++r)
          C[(size_t)(mb + r) * N_DIM + n] = v[r] + bv;
      }
    }
  }
}

// ===========================================================================
// Kernel A: filter MLP (unchanged, verified)
// ===========================================================================
__global__ __launch_bounds__(256)
void filter_gen_kernel(const float* __restrict__ w1, const float* __restrict__ b1,
                       const float* __restrict__ w2, const float* __restrict__ b2,
                       const float* __restrict__ decay, float* __restrict__ h_t)
{
  __shared__ float hid[64][65];
  const int tid  = threadIdx.x;
  const int tau0 = blockIdx.x * 64;
  const int c0   = blockIdx.y * 256;
  {
    const int r = tid & 63;
    const int tb = tid >> 6;
    const float w1v0 = w1[r];
    const float b1v = b1[r];
    float w1c[4], w1s[4];
    #pragma unroll
    for (int p = 0; p < 4; ++p) { w1c[p] = w1[(1 + p) * 64 + r]; w1s[p] = w1[(5 + p) * 64 + r]; }
    #pragma unroll
    for (int i = 0; i < 16; ++i) {
      const int tl = tb + i * 4;
      const int tau = tau0 + tl;
      const float off = (tau < L_SEQ) ? (float)tau : (float)(tau - NFFT);
      float acc = b1v + off * (1.0f / 8192.0f) * w1v0;
      #pragma unroll
      for (int p = 0; p < 4; ++p) {
        const double period = 4.0 + (8188.0 * p) / 3.0;
        const float freq = (float)(6.283185307179586476925287 / period);
        float sp, cp;
        sincosf(off * freq, &sp, &cp);
        acc += cp * w1c[p] + sp * w1s[p];
      }
      hid[r][tl] = sinf(acc);
    }
  }
  __syncthreads();

  const int tx = tid & 63;
  const int ty = tid >> 6;
  const int taug = tau0 + tx;
  const float mt = (taug < L_SEQ) ? (float)taug * (1.0f / 8191.0f)
                                  : (float)(NFFT - 1 - taug) * (1.0f / 8191.0f);
  const int cbase = c0 + ty * 64;
  for (int cb = 0; cb < 8; ++cb) {
    const int c8 = cbase + cb * 8;
    float acc[8];
    #pragma unroll
    for (int jj = 0; jj < 8; ++jj) acc[jj] = b2[c8 + jj];
    for (int rr = 0; rr < 64; ++rr) {
      const float hv = hid[rr][tx];
      const float4 wa = *(const float4*)&w2[rr * 1536 + c8];
      const float4 wb = *(const float4*)&w2[rr * 1536 + c8 + 4];
      acc[0] += hv * wa.x; acc[1] += hv * wa.y; acc[2] += hv * wa.z; acc[3] += hv * wa.w;
      acc[4] += hv * wb.x; acc[5] += hv * wb.y; acc[6] += hv * wb.z; acc[7] += hv * wb.w;
    }
    #pragma unroll
    for (int jj = 0; jj < 8; ++jj) {
      const int c = c8 + jj;
      const float dec = __expf(-mt * fabsf(decay[c]));
      h_t[(size_t)c * NFFT + taug] = acc[jj] * dec;
    }
  }
}

// ===========================================================================
// Kernel B: filter spectra IN PLACE. Final DIF stage fused with bias/scale/
// bf16 pack + 16B global store (no LDS write of the last stage).
// ===========================================================================
__global__ __launch_bounds__(1024)
void filter_fft_kernel(float* __restrict__ hH, const float* __restrict__ bias)
{
  __shared__ float2 c[NPAD];
  const int row = blockIdx.x;
  const int tid = threadIdx.x;
  float* h = hH + (size_t)row * NFFT;
  for (int t = tid; t < NFFT; t += 1024) c[PAD(t)] = make_float2(h[t], 0.0f);
  __syncthreads();
  fft4_fwd_partial<1024>(c, tid);
  const float bo = bias[row];
  const float s = 1.0f / (float)NFFT;
  uint4* Hq = (uint4*)h;
  for (int b = tid; b < NFFT / 4; b += 1024) {
    const int i0 = b << 2;
    float2 a0 = c[PAD(i0)], a1 = c[PAD(i0 + 1)], a2 = c[PAD(i0 + 2)], a3 = c[PAD(i0 + 3)];
    float t0r = a0.x + a2.x, t0i = a0.y + a2.y;
    float t1r = a0.x - a2.x, t1i = a0.y - a2.y;
    float t2r = a1.x + a3.x, t2i = a1.y + a3.y;
    float t3r = a1.x - a3.x, t3i = a1.y - a3.y;
    uint4 w;
    w.x = ((u32)f2bf((t0i + t2i) * s) << 16) | f2bf(((t0r + t2r) + bo) * s);
    w.y = ((u32)f2bf((t1i - t3r) * s) << 16) | f2bf(((t1r + t3i) + bo) * s);
    w.z = ((u32)f2bf((t0i - t2i) * s) << 16) | f2bf(((t0r - t2r) + bo) * s);
    w.w = ((u32)f2bf((t1i + t3r) * s) << 16) | f2bf(((t1r - t3i) + bo) * s);
    Hq[b] = w;
  }
}

// ===========================================================================
// Kernel C: fused shortconv + 2x (FFT conv + gate). 1024 threads, float2 LDS.
// Final-fwd + specmult + first-inv fused in registers (same quad positions);
// gate/zero-pad (o=0) and bf16 v-store (o=1) folded into last inv stage.
// ===========================================================================
__global__ __launch_bounds__(1024)
void fftconv_kernel(const u16* __restrict__ up, float* __restrict__ hH,
                    const float* __restrict__ sw, const float* __restrict__ sb)
{
  __shared__ float2 c[NPAD];
  const int f = blockIdx.x;
  const int tid = threadIdx.x;

  { // pack v = shortconv(up[:, f, :]) for both batches; zero-pad top half
    const u16* u0 = up + (size_t)(0 * C_IN + f) * L_SEQ;
    const u16* u1 = up + (size_t)(1 * C_IN + f) * L_SEQ;
    const float vw0 = sw[f], vw1 = sw[C_IN + f], vw2 = sw[2 * C_IN + f];
    const float vb = sb[f];
    for (int t = tid; t < L_SEQ; t += 1024)
      c[PAD(t)] = make_float2(conv3b(u0, t, vw0, vw1, vw2, vb),
                              conv3b(u1, t, vw0, vw1, vw2, vb));
    for (int t = L_SEQ + tid; t < NFFT; t += 1024)
      c[PAD(t)] = make_float2(0.0f, 0.0f);
  }
  __syncthreads();

  for (int o = 0; o < NORD; ++o) {
    fft4_fwd_partial<1024>(c, tid);

    { // fused: final DIF radix-4 + pointwise *H + first DIT radix-4
      const uint4* Hq = (const uint4*)(hH + (size_t)(o * F_DIM + f) * NFFT);
      for (int b = tid; b < NFFT / 4; b += 1024) {
        const int i0 = b << 2;
        float2 a0 = c[PAD(i0)], a1 = c[PAD(i0+1)], a2 = c[PAD(i0+2)], a3 = c[PAD(i0+3)];
        float t0r = a0.x + a2.x, t0i = a0.y + a2.y;
        float t1r = a0.x - a2.x, t1i = a0.y - a2.y;
        float t2r = a1.x + a3.x, t2i = a1.y + a3.y;
        float t3r = a1.x - a3.x, t3i = a1.y - a3.y;
        float yr[4], yi[4];
        yr[0] = t0r + t2r; yi[0] = t0i + t2i;
        yr[1] = t1r + t3i; yi[1] = t1i - t3r;
        yr[2] = t0r - t2r; yi[2] = t0i - t2i;
        yr[3] = t1r - t3i; yi[3] = t1i + t3r;
        const uint4 hv = Hq[b];
        const u32 hw[4] = {hv.x, hv.y, hv.z, hv.w};
        float ur[4], ui[4];
        #pragma unroll
        for (int k = 0; k < 4; ++k) {
          const float hr = u2f(hw[k] << 16);
          const float hi = u2f(hw[k] & 0xFFFF0000u);
          ur[k] = yr[k] * hr - yi[k] * hi;
          ui[k] = yr[k] * hi + yi[k] * hr;
        }
        float e0r = ur[0] + ur[2], e0i = ui[0] + ui[2];
        float e1r = ur[0] - ur[2], e1i = ui[0] - ui[2];
        float f0r = ur[1] + ur[3], f0i = ui[1] + ui[3];
        float f1r = ur[1] - ur[3], f1i = ui[1] - ui[3];
        c[PAD(i0    )] = make_float2(e0r + f0r, e0i + f0i);
        c[PAD(i0 + 1)] = make_float2(e1r - f1i, e1i + f1r);
        c[PAD(i0 + 2)] = make_float2(e0r - f0r, e0i - f0i);
        c[PAD(i0 + 3)] = make_float2(e1r + f1i, e1i - f1r);
      }
    }
    __syncthreads();

    fft4_inv_mid<1024>(c, tid);

    { // last inv pair (stages 10,12) + gate fold
      const int cc = (o + 1) * F_DIM + f;
      const u16* x0 = up + (size_t)(0 * C_IN + cc) * L_SEQ;
      const u16* x1 = up + (size_t)(1 * C_IN + cc) * L_SEQ;
      const float xw0 = sw[cc], xw1 = sw[C_IN + cc], xw2 = sw[2 * C_IN + cc];
      const float xb = sb[cc];
      u16* v01 = (u16*)(hH + (size_t)f * NFFT);   // row f consumed at o=0

      const int j = tid;                          // q=1024, Q=4096, base=j
      const float stw1 = PI2 / 4096.0f;
      const float stw2 = PI2 / 16384.0f;
      float2 x[4][4];
      #pragma unroll
      for (int k = 0; k < 4; ++k)
        #pragma unroll
        for (int m = 0; m < 4; ++m)
          x[k][m] = c[PAD(j + m * 1024 + k * 4096)];
      {
        float c1, s1, c2, s2, c3, s3;
        rot3(stw1 * (float)j, c1, s1, c2, s2, c3, s3);
        #pragma unroll
        for (int k = 0; k < 4; ++k) {
          float u0r = x[k][0].x, u0i = x[k][0].y;
          float u1r = x[k][1].x*c1 - x[k][1].y*s1, u1i = x[k][1].x*s1 + x[k][1].y*c1;
          float u2r = x[k][2].x*c2 - x[k][2].y*s2, u2i = x[k][2].x*s2 + x[k][2].y*c2;
          float u3r = x[k][3].x*c3 - x[k][3].y*s3, u3i = x[k][3].x*s3 + x[k][3].y*c3;
          float e0r = u0r + u2r, e0i = u0i + u2i;
          float e1r = u0r - u2r, e1i = u0i - u2i;
          float f0r = u1r + u3r, f0i = u1i + u3i;
          float f1r = u1r - u3r, f1i = u1i - u3i;
          x[k][0] = make_float2(e0r + f0r, e0i + f0i);
          x[k][1] = make_float2(e1r - f1i, e1i + f1r);
          x[k][2] = make_float2(e0r - f0r, e0i - f0i);
          x[k][3] = make_float2(e1r + f1i, e1i - f1r);
        }
      }
      #pragma unroll
      for (int m = 0; m < 4; ++m) {
        float c1, s1, c2, s2, c3, s3;
        rot3(stw2 * (float)(j + m * 1024), c1, s1, c2, s2, c3, s3);
        float u0r = x[0][m].x, u0i = x[0][m].y;
        float u1r = x[1][m].x*c1 - x[1][m].y*s1, u1i = x[1][m].x*s1 + x[1][m].y*c1;
        float u2r = x[2][m].x*c2 - x[2][m].y*s2, u2i = x[2][m].x*s2 + x[2][m].y*c2;
        float u3r = x[3][m].x*c3 - x[3][m].y*s3, u3i = x[3][m].x*s3 + x[3][m].y*c3;
        float e0r = u0r + u2r, e0i = u0i + u2i;
        float e1r = u0r - u2r, e1i = u0i - u2i;
        float f0r = u1r + u3r, f0i = u1i + u3i;
        float f1r = u1r - u3r, f1i = u1i - u3i;
        // outputs k=0..3 at t = i0 + k*4096, i0 = j + m*1024 in [0,4096)
        const int t0 = j + m * 1024;
        const int t1 = t0 + 4096;            // t0,t1 < 8192; k=2,3 are padding
        float o0r = e0r + f0r, o0i = e0i + f0i;
        float o1r = e1r - f1i, o1i = e1i + f1r;
        const float g0r = conv3b(x0, t0, xw0, xw1, xw2, xb);
        const float g0i = conv3b(x1, t0, xw0, xw1, xw2, xb);
        const float g1r = conv3b(x0, t1, xw0, xw1, xw2, xb);
        const float g1i = conv3b(x1, t1, xw0, xw1, xw2, xb);
        if (o == 0) {
          c[PAD(t0)]        = make_float2(o0r * g0r, o0i * g0i);
          c[PAD(t1)]        = make_float2(o1r * g1r, o1i * g1i);
          c[PAD(t0 + 8192)] = make_float2(0.0f, 0.0f);
          c[PAD(t1 + 8192)] = make_float2(0.0f, 0.0f);
        } else {
          v01[t0]         = f2bf(o0r * g0r);
          v01[L_SEQ + t0] = f2bf(o0i * g0i);
          v01[t1]         = f2bf(o1r * g1r);
          v01[L_SEQ + t1] = f2bf(o1i * g1i);
        }
      }
      if (o == 0) __syncthreads();
    }
  }
}

// ===========================================================================
extern "C" void kernel_launch(void* const* d_in, const int* in_sizes, int n_in,
                              void* d_out, int out_size, void* d_ws, size_t ws_size,
                              hipStream_t stream)
{
  (void)in_sizes; (void)n_in; (void)out_size; (void)ws_size;
  const float* u     = (const float*)d_in[0];
  const float* fw1   = (const float*)d_in[1];
  const float* fb1   = (const float*)d_in[2];
  const float* fw2   = (const float*)d_in[3];
  const float* fb2   = (const float*)d_in[4];
  const float* decay = (const float*)d_in[5];
  const float* bias  = (const float*)d_in[6];
  const float* ipw   = (const float*)d_in[7];
  const float* ipb   = (const float*)d_in[8];
  const float* sw    = (const float*)d_in[9];
  const float* sb    = (const float*)d_in[10];
  const float* ow    = (const float*)d_in[11];
  const float* ob    = (const float*)d_in[12];
  float* out = (float*)d_out;

  char* ws = (char*)d_ws;
  u16*   up_t  = (u16*)(ws);                                // 75,497,472 B
  float* hH    = (float*)(ws + 75497472);                   // 100,663,296 B
  u16*   u_bf  = (u16*)(ws + 176160768);                    // 25,165,824 B
  u16*   ipw_t = (u16*)(ws + 201326592);                    // 3,538,944 B
  u16*   ow_t  = (u16*)(ws + 204865536);                    // 1,179,648 B
  u16*   vt_t  = (u16*)(ws + 206045184);                    // 25,165,824 B

  cast_bf16_kernel<<<dim3(12288), 256, 0, stream>>>(u, u_bf, (2 * L_SEQ * D_DIM) / 4);
  transpose_cast_kernel<<<dim3(C_IN / 32, D_DIM / 32), 256, 0, stream>>>(ipw, ipw_t, D_DIM, C_IN);
  transpose_cast_kernel<<<dim3(D_DIM / 32, F_DIM / 32), 256, 0, stream>>>(ow, ow_t, F_DIM, D_DIM);

  filter_gen_kernel<<<dim3(NFFT / 64, 1536 / 256), 256, 0, stream>>>(fw1, fb1, fw2, fb2, decay, hH);
  filter_fft_kernel<<<dim3(NORD * F_DIM), 1024, 0, stream>>>(hH, bias);

  mfma_gemm_kernel<C_IN, D_DIM, 0><<<dim3(128, C_IN / 128), 256, 0, stream>>>(u_bf, ipw_t, ipb, up_t);
  fftconv_kernel<<<dim3(F_DIM), 1024, 0, stream>>>(up_t, hH, sw, sb);
  transpose_v_kernel<<<dim3(NFFT / 64, F_DIM / 64), 256, 0, stream>>>((const u16*)hH, vt_t);
  mfma_gemm_kernel<D_DIM, F_DIM, 1><<<dim3(128, D_DIM / 128), 256, 0, stream>>>(vt_t, ow_t, ob, out);
}

// Round 6
// 862.436 us; speedup vs baseline: 1.5901x; 1.5901x over previous
//
#include <hip/hip_runtime.h>
#include <hip/hip_bf16.h>
#include <math.h>

#define L_SEQ 8192
#define NFFT  16384
#define NPAD  16896   // NFFT + NFFT/32 padding (complex elements)
#define F_DIM 768
#define D_DIM 768
#define C_IN  2304   // INNER = F*(ORDER+1)
#define NORD  2
#define PI2   6.2831853071795864769f
#define NTH   512     // 512 thr: VGPR cap 256 -> no spills (r5's 1024 capped at 64 and spilled 2.2GB to scratch)

typedef unsigned short u16;
typedef unsigned int u32;
typedef __attribute__((ext_vector_type(8))) short bf16x8;
typedef __attribute__((ext_vector_type(4))) float f32x4;
struct __align__(8) U16x4 { u16 x, y, z, w; };

__device__ __forceinline__ float bf2f(u16 v) {
  unsigned u = ((unsigned)v) << 16; float f; __builtin_memcpy(&f, &u, 4); return f;
}
__device__ __forceinline__ u16 f2bf(float f) {
  __hip_bfloat16 h = __float2bfloat16(f); u16 r; __builtin_memcpy(&r, &h, 2); return r;
}
__device__ __forceinline__ float u2f(u32 u) { float f; __builtin_memcpy(&f, &u, 4); return f; }

// LDS pad (complex units): +1 complex every 32 -> all FFT strides <=2-way
__device__ __forceinline__ int PAD(int i) { return i + (i >> 5); }

__device__ __forceinline__ void rot3(float ang, float& c1, float& s1,
                                     float& c2, float& s2, float& c3, float& s3)
{
  __sincosf(ang, &s1, &c1);
  c2 = c1 * c1 - s1 * s1; s2 = 2.0f * c1 * s1;
  c3 = c1 * c2 - s1 * s2; s3 = c1 * s2 + s1 * c2;
}

// ===========================================================================
// Radix-4 FFT over padded float2 LDS, N = 16384 = 4^7, fused stage pairs.
// fwd partial: DIF stages (12,10)(8,6)(4,2) -- caller fuses final stage 0.
// inv: caller fuses stage 0; inv_mid does (2,4)(6,8); caller fuses (10,12).
// Algebra transcribed 1:1 from the round-2..5 verified routines.
// ===========================================================================
template<int NT>
__device__ __forceinline__ void fft4_fwd_partial(float2* c, int tid)
{
  #pragma unroll
  for (int lq = 12; lq >= 4; lq -= 4) {      // fused pair: stage lq then lq-2
    const int q  = 1 << lq;
    const int q4 = q >> 2;
    const float stw1 = -PI2 / (float)(q << 2);
    const float stw2 = -PI2 / (float)q;
    for (int g = tid; g < NFFT / 16; g += NT) {
      const int j    = g & (q4 - 1);
      const int base = ((g >> (lq - 2)) << (lq + 2)) + j;
      float2 x[4][4];                        // [k][m]: pos = base + m*q4 + k*q
      #pragma unroll
      for (int k = 0; k < 4; ++k)
        #pragma unroll
        for (int m = 0; m < 4; ++m)
          x[k][m] = c[PAD(base + m * q4 + k * q)];
      #pragma unroll
      for (int m = 0; m < 4; ++m) {          // layer 1: stage lq, j1 = j+m*q4
        float t0r = x[0][m].x + x[2][m].x, t0i = x[0][m].y + x[2][m].y;
        float t1r = x[0][m].x - x[2][m].x, t1i = x[0][m].y - x[2][m].y;
        float t2r = x[1][m].x + x[3][m].x, t2i = x[1][m].y + x[3][m].y;
        float t3r = x[1][m].x - x[3][m].x, t3i = x[1][m].y - x[3][m].y;
        float y0r = t0r + t2r, y0i = t0i + t2i;
        float y1r = t1r + t3i, y1i = t1i - t3r;
        float y2r = t0r - t2r, y2i = t0i - t2i;
        float y3r = t1r - t3i, y3i = t1i + t3r;
        float c1, s1, c2, s2, c3, s3;
        rot3(stw1 * (float)(j + m * q4), c1, s1, c2, s2, c3, s3);
        x[0][m] = make_float2(y0r, y0i);
        x[1][m] = make_float2(y1r * c1 - y1i * s1, y1r * s1 + y1i * c1);
        x[2][m] = make_float2(y2r * c2 - y2i * s2, y2r * s2 + y2i * c2);
        x[3][m] = make_float2(y3r * c3 - y3i * s3, y3r * s3 + y3i * c3);
      }
      float c1, s1, c2, s2, c3, s3;          // layer 2: stage lq-2, j2 = j
      rot3(stw2 * (float)j, c1, s1, c2, s2, c3, s3);
      #pragma unroll
      for (int k = 0; k < 4; ++k) {
        float t0r = x[k][0].x + x[k][2].x, t0i = x[k][0].y + x[k][2].y;
        float t1r = x[k][0].x - x[k][2].x, t1i = x[k][0].y - x[k][2].y;
        float t2r = x[k][1].x + x[k][3].x, t2i = x[k][1].y + x[k][3].y;
        float t3r = x[k][1].x - x[k][3].x, t3i = x[k][1].y - x[k][3].y;
        float y0r = t0r + t2r, y0i = t0i + t2i;
        float y1r = t1r + t3i, y1i = t1i - t3r;
        float y2r = t0r - t2r, y2i = t0i - t2i;
        float y3r = t1r - t3i, y3i = t1i + t3r;
        const int i0 = base + k * q;
        c[PAD(i0         )] = make_float2(y0r, y0i);
        c[PAD(i0 +     q4)] = make_float2(y1r*c1 - y1i*s1, y1r*s1 + y1i*c1);
        c[PAD(i0 + 2 * q4)] = make_float2(y2r*c2 - y2i*s2, y2r*s2 + y2i*c2);
        c[PAD(i0 + 3 * q4)] = make_float2(y3r*c3 - y3i*s3, y3r*s3 + y3i*c3);
      }
    }
    __syncthreads();
  }
}

template<int NT>
__device__ __forceinline__ void fft4_inv_mid(float2* c, int tid)
{
  #pragma unroll
  for (int lq = 2; lq <= 6; lq += 4) {       // fused pair: stage lq then lq+2
    const int q = 1 << lq;
    const int Q = q << 2;
    const float stw1 = PI2 / (float)(q << 2);
    const float stw2 = PI2 / (float)(Q << 2);
    for (int g = tid; g < NFFT / 16; g += NT) {
      const int j    = g & (q - 1);
      const int base = ((g >> lq) << (lq + 4)) + j;
      float2 x[4][4];                        // [k][m]: pos = base + m*q + k*Q
      #pragma unroll
      for (int k = 0; k < 4; ++k)
        #pragma unroll
        for (int m = 0; m < 4; ++m)
          x[k][m] = c[PAD(base + m * q + k * Q)];
      {                                       // layer 1: stage lq, twiddle j
        float c1, s1, c2, s2, c3, s3;
        rot3(stw1 * (float)j, c1, s1, c2, s2, c3, s3);
        #pragma unroll
        for (int k = 0; k < 4; ++k) {
          float u0r = x[k][0].x, u0i = x[k][0].y;
          float u1r = x[k][1].x*c1 - x[k][1].y*s1, u1i = x[k][1].x*s1 + x[k][1].y*c1;
          float u2r = x[k][2].x*c2 - x[k][2].y*s2, u2i = x[k][2].x*s2 + x[k][2].y*c2;
          float u3r = x[k][3].x*c3 - x[k][3].y*s3, u3i = x[k][3].x*s3 + x[k][3].y*c3;
          float e0r = u0r + u2r, e0i = u0i + u2i;
          float e1r = u0r - u2r, e1i = u0i - u2i;
          float f0r = u1r + u3r, f0i = u1i + u3i;
          float f1r = u1r - u3r, f1i = u1i - u3i;
          x[k][0] = make_float2(e0r + f0r, e0i + f0i);
          x[k][1] = make_float2(e1r - f1i, e1i + f1r);
          x[k][2] = make_float2(e0r - f0r, e0i - f0i);
          x[k][3] = make_float2(e1r + f1i, e1i - f1r);
        }
      }
      #pragma unroll
      for (int m = 0; m < 4; ++m) {           // layer 2: stage lq+2, j2 = j+m*q
        float c1, s1, c2, s2, c3, s3;
        rot3(stw2 * (float)(j + m * q), c1, s1, c2, s2, c3, s3);
        float u0r = x[0][m].x, u0i = x[0][m].y;
        float u1r = x[1][m].x*c1 - x[1][m].y*s1, u1i = x[1][m].x*s1 + x[1][m].y*c1;
        float u2r = x[2][m].x*c2 - x[2][m].y*s2, u2i = x[2][m].x*s2 + x[2][m].y*c2;
        float u3r = x[3][m].x*c3 - x[3][m].y*s3, u3i = x[3][m].x*s3 + x[3][m].y*c3;
        float e0r = u0r + u2r, e0i = u0i + u2i;
        float e1r = u0r - u2r, e1i = u0i - u2i;
        float f0r = u1r + u3r, f0i = u1i + u3i;
        float f1r = u1r - u3r, f1i = u1i - u3i;
        const int i0 = base + m * q;
        c[PAD(i0        )] = make_float2(e0r + f0r, e0i + f0i);
        c[PAD(i0 +     Q)] = make_float2(e1r - f1i, e1i + f1r);
        c[PAD(i0 + 2 * Q)] = make_float2(e0r - f0r, e0i - f0i);
        c[PAD(i0 + 3 * Q)] = make_float2(e1r + f1i, e1i - f1r);
      }
    }
    __syncthreads();
  }
}

// depthwise conv3 on a bf16 row, SAME padding (XLA cross-correlation)
__device__ __forceinline__ float conv3b(const u16* __restrict__ row, int t,
                                        float w0, float w1, float w2, float sb)
{
  float l = (t > 0)         ? bf2f(row[t - 1]) : 0.0f;
  float c = bf2f(row[t]);
  float r = (t < L_SEQ - 1) ? bf2f(row[t + 1]) : 0.0f;
  return w0 * l + w1 * c + w2 * r + sb;
}

// ===========================================================================
// Prep kernels (unchanged)
// ===========================================================================
__global__ __launch_bounds__(256)
void cast_bf16_kernel(const float* __restrict__ in, u16* __restrict__ out, int n4)
{
  int i = blockIdx.x * 256 + threadIdx.x;
  if (i < n4) {
    float4 v = ((const float4*)in)[i];
    U16x4 w; w.x = f2bf(v.x); w.y = f2bf(v.y); w.z = f2bf(v.z); w.w = f2bf(v.w);
    ((U16x4*)out)[i] = w;
  }
}

__global__ __launch_bounds__(256)
void transpose_cast_kernel(const float* __restrict__ in, u16* __restrict__ out,
                           int K, int N)   // in [K][N] fp32 -> out [N][K] bf16
{
  __shared__ u16 tile[32][33];
  const int n0 = blockIdx.x * 32, k0 = blockIdx.y * 32;
  const int tx = threadIdx.x & 31, ty = threadIdx.x >> 5;
  #pragma unroll
  for (int i = 0; i < 32; i += 8)
    tile[ty + i][tx] = f2bf(in[(size_t)(k0 + ty + i) * N + n0 + tx]);
  __syncthreads();
  #pragma unroll
  for (int i = 0; i < 32; i += 8)
    out[(size_t)(n0 + ty + i) * K + k0 + tx] = tile[tx][ty + i];
}

__global__ __launch_bounds__(256)
void transpose_v_kernel(const u16* __restrict__ vb, u16* __restrict__ out)
{
  __shared__ u16 t2[64][65];
  const int m0 = blockIdx.x * 64, f0 = blockIdx.y * 64;
  const int tx = threadIdx.x & 63, ty = threadIdx.x >> 6;
  #pragma unroll
  for (int i = 0; i < 64; i += 4)
    t2[ty + i][tx] = vb[(size_t)(f0 + ty + i) * (2 * NFFT) + m0 + tx];
  __syncthreads();
  #pragma unroll
  for (int i = 0; i < 64; i += 4)
    out[(size_t)(m0 + ty + i) * F_DIM + f0 + tx] = t2[tx][ty + i];
}

// ===========================================================================
// MFMA GEMM (unchanged, verified rounds 3-5)
// ===========================================================================
template<int N_DIM, int K_DIM, int WMODE>
__global__ __launch_bounds__(256)
void mfma_gemm_kernel(const u16* __restrict__ A, const u16* __restrict__ B,
                      const float* __restrict__ bias, void* __restrict__ Cv)
{
  constexpr int BK = 64;
  __shared__ u16 As[128 * BK];
  __shared__ u16 Bs[128 * BK];
  const int tid  = threadIdx.x;
  const int lane = tid & 63;
  const int wid  = tid >> 6;
  const int m0 = blockIdx.x * 128;
  const int n0 = blockIdx.y * 128;

  const u16* aPtr[4]; const u16* bPtr[4];
  #pragma unroll
  for (int i = 0; i < 4; ++i) {
    const int g = tid + (i << 8);
    aPtr[i] = A + (size_t)(m0 + (g >> 3)) * K_DIM + ((g & 7) << 3);
    bPtr[i] = B + (size_t)(n0 + (g >> 3)) * K_DIM + ((g & 7) << 3);
  }

  const int wm = (wid & 1) << 6;
  const int wn = (wid >> 1) << 6;
  int aoff[4], boff[4];
  #pragma unroll
  for (int f = 0; f < 4; ++f) {
    aoff[f] = (wm + f * 16 + (lane & 15)) * BK + ((lane >> 4) << 3);
    boff[f] = (wn + f * 16 + (lane & 15)) * BK + ((lane >> 4) << 3);
  }

  f32x4 acc[4][4];
  #pragma unroll
  for (int i = 0; i < 4; ++i)
    #pragma unroll
    for (int j = 0; j < 4; ++j)
      acc[i][j] = (f32x4){0.f, 0.f, 0.f, 0.f};

  for (int k0 = 0; k0 < K_DIM; k0 += BK) {
    #pragma unroll
    for (int i = 0; i < 4; ++i) {
      __builtin_amdgcn_global_load_lds(
          (const __attribute__((address_space(1))) void*)aPtr[i],
          (__attribute__((address_space(3))) void*)&As[(((wid << 6) + (i << 8)) << 3)],
          16, 0, 0);
      aPtr[i] += BK;
    }
    #pragma unroll
    for (int i = 0; i < 4; ++i) {
      __builtin_amdgcn_global_load_lds(
          (const __attribute__((address_space(1))) void*)bPtr[i],
          (__attribute__((address_space(3))) void*)&Bs[(((wid << 6) + (i << 8)) << 3)],
          16, 0, 0);
      bPtr[i] += BK;
    }
    __syncthreads();
    #pragma unroll
    for (int kk = 0; kk < 2; ++kk) {
      bf16x8 af[4], bg[4];
      #pragma unroll
      for (int f = 0; f < 4; ++f) af[f] = *(const bf16x8*)&As[aoff[f] + kk * 32];
      #pragma unroll
      for (int f = 0; f < 4; ++f) bg[f] = *(const bf16x8*)&Bs[boff[f] + kk * 32];
      #pragma unroll
      for (int fm = 0; fm < 4; ++fm)
        #pragma unroll
        for (int fn = 0; fn < 4; ++fn)
          acc[fm][fn] = __builtin_amdgcn_mfma_f32_16x16x32_bf16(
              af[fm], bg[fn], acc[fm][fn], 0, 0, 0);
    }
    __syncthreads();
  }

  if (WMODE == 0) {
    u16* C = (u16*)Cv;
    const int b = m0 >> 13;
    const int tbase = (m0 & (L_SEQ - 1)) + wm + ((lane >> 4) << 2);
    #pragma unroll
    for (int fn = 0; fn < 4; ++fn) {
      const int n = n0 + wn + fn * 16 + (lane & 15);
      const float bv = bias[n];
      u16* row = C + ((size_t)b * N_DIM + n) * L_SEQ;
      #pragma unroll
      for (int fm = 0; fm < 4; ++fm) {
        f32x4 v = acc[fm][fn];
        U16x4 w;
        w.x = f2bf(v[0] + bv); w.y = f2bf(v[1] + bv);
        w.z = f2bf(v[2] + bv); w.w = f2bf(v[3] + bv);
        *(U16x4*)&row[tbase + fm * 16] = w;
      }
    }
  } else {
    float* C = (float*)Cv;
    #pragma unroll
    for (int fn = 0; fn < 4; ++fn) {
      const int n = n0 + wn + fn * 16 + (lane & 15);
      const float bv = bias[n];
      #pragma unroll
      for (int fm = 0; fm < 4; ++fm) {
        const int mb = m0 + wm + fm * 16 + ((lane >> 4) << 2);
        f32x4 v = acc[fm][fn];
        #pragma unroll
        for (int r = 0; r < 4; ++r)
          C[(size_t)(mb + r) * N_DIM + n] = v[r] + bv;
      }
    }
  }
}

// ===========================================================================
// Kernel A: filter MLP (unchanged, verified)
// ===========================================================================
__global__ __launch_bounds__(256)
void filter_gen_kernel(const float* __restrict__ w1, const float* __restrict__ b1,
                       const float* __restrict__ w2, const float* __restrict__ b2,
                       const float* __restrict__ decay, float* __restrict__ h_t)
{
  __shared__ float hid[64][65];
  const int tid  = threadIdx.x;
  const int tau0 = blockIdx.x * 64;
  const int c0   = blockIdx.y * 256;
  {
    const int r = tid & 63;
    const int tb = tid >> 6;
    const float w1v0 = w1[r];
    const float b1v = b1[r];
    float w1c[4], w1s[4];
    #pragma unroll
    for (int p = 0; p < 4; ++p) { w1c[p] = w1[(1 + p) * 64 + r]; w1s[p] = w1[(5 + p) * 64 + r]; }
    #pragma unroll
    for (int i = 0; i < 16; ++i) {
      const int tl = tb + i * 4;
      const int tau = tau0 + tl;
      const float off = (tau < L_SEQ) ? (float)tau : (float)(tau - NFFT);
      float acc = b1v + off * (1.0f / 8192.0f) * w1v0;
      #pragma unroll
      for (int p = 0; p < 4; ++p) {
        const double period = 4.0 + (8188.0 * p) / 3.0;
        const float freq = (float)(6.283185307179586476925287 / period);
        float sp, cp;
        sincosf(off * freq, &sp, &cp);
        acc += cp * w1c[p] + sp * w1s[p];
      }
      hid[r][tl] = sinf(acc);
    }
  }
  __syncthreads();

  const int tx = tid & 63;
  const int ty = tid >> 6;
  const int taug = tau0 + tx;
  const float mt = (taug < L_SEQ) ? (float)taug * (1.0f / 8191.0f)
                                  : (float)(NFFT - 1 - taug) * (1.0f / 8191.0f);
  const int cbase = c0 + ty * 64;
  for (int cb = 0; cb < 8; ++cb) {
    const int c8 = cbase + cb * 8;
    float acc[8];
    #pragma unroll
    for (int jj = 0; jj < 8; ++jj) acc[jj] = b2[c8 + jj];
    for (int rr = 0; rr < 64; ++rr) {
      const float hv = hid[rr][tx];
      const float4 wa = *(const float4*)&w2[rr * 1536 + c8];
      const float4 wb = *(const float4*)&w2[rr * 1536 + c8 + 4];
      acc[0] += hv * wa.x; acc[1] += hv * wa.y; acc[2] += hv * wa.z; acc[3] += hv * wa.w;
      acc[4] += hv * wb.x; acc[5] += hv * wb.y; acc[6] += hv * wb.z; acc[7] += hv * wb.w;
    }
    #pragma unroll
    for (int jj = 0; jj < 8; ++jj) {
      const int c = c8 + jj;
      const float dec = __expf(-mt * fabsf(decay[c]));
      h_t[(size_t)c * NFFT + taug] = acc[jj] * dec;
    }
  }
}

// ===========================================================================
// Kernel B: filter spectra IN PLACE. Final DIF stage fused with bias/scale/
// bf16 pack + 16B global store.
// ===========================================================================
__global__ __launch_bounds__(NTH)
void filter_fft_kernel(float* __restrict__ hH, const float* __restrict__ bias)
{
  __shared__ float2 c[NPAD];
  const int row = blockIdx.x;
  const int tid = threadIdx.x;
  float* h = hH + (size_t)row * NFFT;
  for (int t = tid; t < NFFT; t += NTH) c[PAD(t)] = make_float2(h[t], 0.0f);
  __syncthreads();
  fft4_fwd_partial<NTH>(c, tid);
  const float bo = bias[row];
  const float s = 1.0f / (float)NFFT;
  uint4* Hq = (uint4*)h;
  for (int b = tid; b < NFFT / 4; b += NTH) {
    const int i0 = b << 2;
    float2 a0 = c[PAD(i0)], a1 = c[PAD(i0 + 1)], a2 = c[PAD(i0 + 2)], a3 = c[PAD(i0 + 3)];
    float t0r = a0.x + a2.x, t0i = a0.y + a2.y;
    float t1r = a0.x - a2.x, t1i = a0.y - a2.y;
    float t2r = a1.x + a3.x, t2i = a1.y + a3.y;
    float t3r = a1.x - a3.x, t3i = a1.y - a3.y;
    uint4 w;
    w.x = ((u32)f2bf((t0i + t2i) * s) << 16) | f2bf(((t0r + t2r) + bo) * s);
    w.y = ((u32)f2bf((t1i - t3r) * s) << 16) | f2bf(((t1r + t3i) + bo) * s);
    w.z = ((u32)f2bf((t0i - t2i) * s) << 16) | f2bf(((t0r - t2r) + bo) * s);
    w.w = ((u32)f2bf((t1i + t3r) * s) << 16) | f2bf(((t1r - t3i) + bo) * s);
    Hq[b] = w;
  }
}

// ===========================================================================
// Kernel C: fused shortconv + 2x (FFT conv + gate). 512 threads, float2 LDS.
// Final-fwd + specmult + first-inv fused in registers (same quad positions);
// gate/zero-pad (o=0) and bf16 v-store (o=1) folded into last inv stage pair.
// ===========================================================================
__global__ __launch_bounds__(NTH)
void fftconv_kernel(const u16* __restrict__ up, float* __restrict__ hH,
                    const float* __restrict__ sw, const float* __restrict__ sb)
{
  __shared__ float2 c[NPAD];
  const int f = blockIdx.x;
  const int tid = threadIdx.x;

  { // pack v = shortconv(up[:, f, :]) for both batches; zero-pad top half
    const u16* u0 = up + (size_t)(0 * C_IN + f) * L_SEQ;
    const u16* u1 = up + (size_t)(1 * C_IN + f) * L_SEQ;
    const float vw0 = sw[f], vw1 = sw[C_IN + f], vw2 = sw[2 * C_IN + f];
    const float vb = sb[f];
    for (int t = tid; t < L_SEQ; t += NTH)
      c[PAD(t)] = make_float2(conv3b(u0, t, vw0, vw1, vw2, vb),
                              conv3b(u1, t, vw0, vw1, vw2, vb));
    for (int t = L_SEQ + tid; t < NFFT; t += NTH)
      c[PAD(t)] = make_float2(0.0f, 0.0f);
  }
  __syncthreads();

  for (int o = 0; o < NORD; ++o) {
    fft4_fwd_partial<NTH>(c, tid);

    { // fused: final DIF radix-4 + pointwise *H + first DIT radix-4
      const uint4* Hq = (const uint4*)(hH + (size_t)(o * F_DIM + f) * NFFT);
      for (int b = tid; b < NFFT / 4; b += NTH) {
        const int i0 = b << 2;
        float2 a0 = c[PAD(i0)], a1 = c[PAD(i0+1)], a2 = c[PAD(i0+2)], a3 = c[PAD(i0+3)];
        float t0r = a0.x + a2.x, t0i = a0.y + a2.y;
        float t1r = a0.x - a2.x, t1i = a0.y - a2.y;
        float t2r = a1.x + a3.x, t2i = a1.y + a3.y;
        float t3r = a1.x - a3.x, t3i = a1.y - a3.y;
        float yr[4], yi[4];
        yr[0] = t0r + t2r; yi[0] = t0i + t2i;
        yr[1] = t1r + t3i; yi[1] = t1i - t3r;
        yr[2] = t0r - t2r; yi[2] = t0i - t2i;
        yr[3] = t1r - t3i; yi[3] = t1i + t3r;
        const uint4 hv = Hq[b];
        const u32 hw[4] = {hv.x, hv.y, hv.z, hv.w};
        float ur[4], ui[4];
        #pragma unroll
        for (int k = 0; k < 4; ++k) {
          const float hr = u2f(hw[k] << 16);
          const float hi = u2f(hw[k] & 0xFFFF0000u);
          ur[k] = yr[k] * hr - yi[k] * hi;
          ui[k] = yr[k] * hi + yi[k] * hr;
        }
        float e0r = ur[0] + ur[2], e0i = ui[0] + ui[2];
        float e1r = ur[0] - ur[2], e1i = ui[0] - ui[2];
        float f0r = ur[1] + ur[3], f0i = ui[1] + ui[3];
        float f1r = ur[1] - ur[3], f1i = ui[1] - ui[3];
        c[PAD(i0    )] = make_float2(e0r + f0r, e0i + f0i);
        c[PAD(i0 + 1)] = make_float2(e1r - f1i, e1i + f1r);
        c[PAD(i0 + 2)] = make_float2(e0r - f0r, e0i - f0i);
        c[PAD(i0 + 3)] = make_float2(e1r + f1i, e1i - f1r);
      }
    }
    __syncthreads();

    fft4_inv_mid<NTH>(c, tid);

    { // last inv pair (stages 10,12) + gate fold; j-classes are disjoint
      // across threads/iterations so no barrier inside the loop
      const int cc = (o + 1) * F_DIM + f;
      const u16* x0 = up + (size_t)(0 * C_IN + cc) * L_SEQ;
      const u16* x1 = up + (size_t)(1 * C_IN + cc) * L_SEQ;
      const float xw0 = sw[cc], xw1 = sw[C_IN + cc], xw2 = sw[2 * C_IN + cc];
      const float xb = sb[cc];
      u16* v01 = (u16*)(hH + (size_t)f * NFFT);   // row f consumed at o=0

      const float stw1 = PI2 / 4096.0f;
      const float stw2 = PI2 / 16384.0f;
      for (int j = tid; j < 1024; j += NTH) {     // q=1024, Q=4096, base=j
        float2 x[4][4];
        #pragma unroll
        for (int k = 0; k < 4; ++k)
          #pragma unroll
          for (int m = 0; m < 4; ++m)
            x[k][m] = c[PAD(j + m * 1024 + k * 4096)];
        {
          float c1, s1, c2, s2, c3, s3;
          rot3(stw1 * (float)j, c1, s1, c2, s2, c3, s3);
          #pragma unroll
          for (int k = 0; k < 4; ++k) {
            float u0r = x[k][0].x, u0i = x[k][0].y;
            float u1r = x[k][1].x*c1 - x[k][1].y*s1, u1i = x[k][1].x*s1 + x[k][1].y*c1;
            float u2r = x[k][2].x*c2 - x[k][2].y*s2, u2i = x[k][2].x*s2 + x[k][2].y*c2;
            float u3r = x[k][3].x*c3 - x[k][3].y*s3, u3i = x[k][3].x*s3 + x[k][3].y*c3;
            float e0r = u0r + u2r, e0i = u0i + u2i;
            float e1r = u0r - u2r, e1i = u0i - u2i;
            float f0r = u1r + u3r, f0i = u1i + u3i;
            float f1r = u1r - u3r, f1i = u1i - u3i;
            x[k][0] = make_float2(e0r + f0r, e0i + f0i);
            x[k][1] = make_float2(e1r - f1i, e1i + f1r);
            x[k][2] = make_float2(e0r - f0r, e0i - f0i);
            x[k][3] = make_float2(e1r + f1i, e1i - f1r);
          }
        }
        #pragma unroll
        for (int m = 0; m < 4; ++m) {
          float c1, s1, c2, s2, c3, s3;
          rot3(stw2 * (float)(j + m * 1024), c1, s1, c2, s2, c3, s3);
          float u0r = x[0][m].x, u0i = x[0][m].y;
          float u1r = x[1][m].x*c1 - x[1][m].y*s1, u1i = x[1][m].x*s1 + x[1][m].y*c1;
          float u2r = x[2][m].x*c2 - x[2][m].y*s2, u2i = x[2][m].x*s2 + x[2][m].y*c2;
          float u3r = x[3][m].x*c3 - x[3][m].y*s3, u3i = x[3][m].x*s3 + x[3][m].y*c3;
          float e0r = u0r + u2r, e0i = u0i + u2i;
          float e1r = u0r - u2r, e1i = u0i - u2i;
          float f0r = u1r + u3r, f0i = u1i + u3i;
          float f1r = u1r - u3r, f1i = u1i - u3i;
          // outputs at t = (j + m*1024) + k*4096; k=2,3 land in padding
          const int t0 = j + m * 1024;
          const int t1 = t0 + 4096;
          float o0r = e0r + f0r, o0i = e0i + f0i;
          float o1r = e1r - f1i, o1i = e1i + f1r;
          const float g0r = conv3b(x0, t0, xw0, xw1, xw2, xb);
          const float g0i = conv3b(x1, t0, xw0, xw1, xw2, xb);
          const float g1r = conv3b(x0, t1, xw0, xw1, xw2, xb);
          const float g1i = conv3b(x1, t1, xw0, xw1, xw2, xb);
          if (o == 0) {
            c[PAD(t0)]        = make_float2(o0r * g0r, o0i * g0i);
            c[PAD(t1)]        = make_float2(o1r * g1r, o1i * g1i);
            c[PAD(t0 + 8192)] = make_float2(0.0f, 0.0f);
            c[PAD(t1 + 8192)] = make_float2(0.0f, 0.0f);
          } else {
            v01[t0]         = f2bf(o0r * g0r);
            v01[L_SEQ + t0] = f2bf(o0i * g0i);
            v01[t1]         = f2bf(o1r * g1r);
            v01[L_SEQ + t1] = f2bf(o1i * g1i);
          }
        }
      }
      if (o == 0) __syncthreads();
    }
  }
}

// ===========================================================================
extern "C" void kernel_launch(void* const* d_in, const int* in_sizes, int n_in,
                              void* d_out, int out_size, void* d_ws, size_t ws_size,
                              hipStream_t stream)
{
  (void)in_sizes; (void)n_in; (void)out_size; (void)ws_size;
  const float* u     = (const float*)d_in[0];
  const float* fw1   = (const float*)d_in[1];
  const float* fb1   = (const float*)d_in[2];
  const float* fw2   = (const float*)d_in[3];
  const float* fb2   = (const float*)d_in[4];
  const float* decay = (const float*)d_in[5];
  const float* bias  = (const float*)d_in[6];
  const float* ipw   = (const float*)d_in[7];
  const float* ipb   = (const float*)d_in[8];
  const float* sw    = (const float*)d_in[9];
  const float* sb    = (const float*)d_in[10];
  const float* ow    = (const float*)d_in[11];
  const float* ob    = (const float*)d_in[12];
  float* out = (float*)d_out;

  char* ws = (char*)d_ws;
  u16*   up_t  = (u16*)(ws);                                // 75,497,472 B
  float* hH    = (float*)(ws + 75497472);                   // 100,663,296 B
  u16*   u_bf  = (u16*)(ws + 176160768);                    // 25,165,824 B
  u16*   ipw_t = (u16*)(ws + 201326592);                    // 3,538,944 B
  u16*   ow_t  = (u16*)(ws + 204865536);                    // 1,179,648 B
  u16*   vt_t  = (u16*)(ws + 206045184);                    // 25,165,824 B

  cast_bf16_kernel<<<dim3(12288), 256, 0, stream>>>(u, u_bf, (2 * L_SEQ * D_DIM) / 4);
  transpose_cast_kernel<<<dim3(C_IN / 32, D_DIM / 32), 256, 0, stream>>>(ipw, ipw_t, D_DIM, C_IN);
  transpose_cast_kernel<<<dim3(D_DIM / 32, F_DIM / 32), 256, 0, stream>>>(ow, ow_t, F_DIM, D_DIM);

  filter_gen_kernel<<<dim3(NFFT / 64, 1536 / 256), 256, 0, stream>>>(fw1, fb1, fw2, fb2, decay, hH);
  filter_fft_kernel<<<dim3(NORD * F_DIM), NTH, 0, stream>>>(hH, bias);

  mfma_gemm_kernel<C_IN, D_DIM, 0><<<dim3(128, C_IN / 128), 256, 0, stream>>>(u_bf, ipw_t, ipb, up_t);
  fftconv_kernel<<<dim3(F_DIM), NTH, 0, stream>>>(up_t, hH, sw, sb);
  transpose_v_kernel<<<dim3(NFFT / 64, F_DIM / 64), 256, 0, stream>>>((const u16*)hH, vt_t);
  mfma_gemm_kernel<D_DIM, F_DIM, 1><<<dim3(128, D_DIM / 128), 256, 0, stream>>>(vt_t, ow_t, ob, out);
}